// Round 1
// 736.187 us; speedup vs baseline: 1.0036x; 1.0036x over previous
//
#include <hip/hip_runtime.h>
#include <hip/hip_bf16.h>
#include <math.h>
#include <stdint.h>

// ---------- constants ----------
#define C_ 384
#define TOKENS 50176          // B*H*W = 16*56*56 = 16*64*49

typedef __bf16 bf16;
typedef __bf16 bf16x8 __attribute__((ext_vector_type(8)));
typedef __bf16 bf16x4 __attribute__((ext_vector_type(4)));
typedef float  f32x4  __attribute__((ext_vector_type(4)));

__device__ __forceinline__ float b2f(bf16 x) { return (float)x; }
__device__ __forceinline__ bf16  f2b(float x) { return (bf16)x; }

// tanh-form GELU: v * sigmoid(1.5957691 v + 0.0713548 v^3)
// max |diff vs exact erf-GELU| < 1e-4 for |v|<3.5; safe at bf16 output precision.
__device__ __forceinline__ float fast_gelu(float v) {
    float u2 = v * fmaf(v * v, 0.07135481f, 1.5957691f);
    return v / (1.0f + __expf(-u2));
}

// async global->LDS, 16 bytes per lane. LDS dest must be wave-uniform base + lane*16.
__device__ __forceinline__ void gld_lds16(const bf16* g, bf16* l) {
    __builtin_amdgcn_global_load_lds(
        (const __attribute__((address_space(1))) void*)g,
        (__attribute__((address_space(3))) void*)l, 16, 0, 0);
}

// ---------- K0: weight convert+transpose: in f32 [K][N] -> out bf16 [N][K] ----------
__global__ void wtrans_kernel(const float* __restrict__ in, bf16* __restrict__ out,
                              int K, int N) {
    int idx = blockIdx.x * 256 + threadIdx.x;
    if (idx >= K * N) return;
    int n = idx / K, k = idx % K;
    out[idx] = f2b(in[(size_t)k * N + n]);
}

// ---------- K1: LN1 + roll(-3,-3) + window partition. x BCHW f32 -> xw [50176][384] bf16 ----------
__global__ __launch_bounds__(256) void ln1_gather_kernel(
    const float* __restrict__ x, const float* __restrict__ g,
    const float* __restrict__ bt, bf16* __restrict__ xw) {
    int wave = threadIdx.x >> 6, lane = threadIdx.x & 63;
    int T = blockIdx.x * 4 + wave;
    int wi = T / 49, n = T % 49;
    int b = wi >> 6, w64 = wi & 63;
    int bh = w64 >> 3, bw = w64 & 7;
    int hs = bh * 7 + n / 7 + 3; if (hs >= 56) hs -= 56;
    int wsd = bw * 7 + n % 7 + 3; if (wsd >= 56) wsd -= 56;
    const float* xp = x + (size_t)b * C_ * 3136 + hs * 56 + wsd;
    float v[6];
    #pragma unroll
    for (int k = 0; k < 6; k++) v[k] = xp[(size_t)(lane + k * 64) * 3136];
    float s = v[0] + v[1] + v[2] + v[3] + v[4] + v[5];
    #pragma unroll
    for (int m = 32; m; m >>= 1) s += __shfl_xor(s, m);
    float mu = s * (1.0f / 384.0f);
    float s2 = 0.f;
    #pragma unroll
    for (int k = 0; k < 6; k++) { float d = v[k] - mu; s2 += d * d; }
    #pragma unroll
    for (int m = 32; m; m >>= 1) s2 += __shfl_xor(s2, m);
    float rstd = rsqrtf(s2 * (1.0f / 384.0f) + 1e-5f);
    bf16* op = xw + (size_t)T * 384;
    #pragma unroll
    for (int k = 0; k < 6; k++) {
        int c = lane + k * 64;
        op[c] = f2b((v[k] - mu) * rstd * g[c] + bt[c]);
    }
}

// ---------- GEMM: C[M][N] = A[M][K] @ Wt[N][K]^T + bias, 128x128 tile, BK=64 ----------
// Staging uses XOR-swizzled global source + linear global_load_lds dest + swizzled
// ds_read (rule 21): group g at row r holds global group g^(r&7); frag reads XOR back.
// MFMA operands are SWAPPED (acc[j][i] = mfma(B,A)) so each thread's 4 acc regs are 4
// consecutive output COLUMNS at a fixed row -> 8B vectorized stores/bias/residual.
enum { EPI_NONE = 0, EPI_GELU = 1, EPI_PROJ = 2, EPI_FC2 = 3 };

template <int EPI>
__global__ __launch_bounds__(256) void gemm_kernel(
    const bf16* __restrict__ A, const bf16* __restrict__ Wt,
    const float* __restrict__ bias, bf16* __restrict__ Cout,
    int Kdim, int Ndim,
    const float* __restrict__ resx,   // EPI_PROJ: x in BCHW f32
    const bf16* __restrict__ resb) {  // EPI_FC2 : x2 token-major bf16
    __shared__ __align__(16) bf16 As[128 * 64];
    __shared__ __align__(16) bf16 Bs[128 * 64];
    int t = threadIdx.x;
    int m0 = blockIdx.x * 128, n0 = blockIdx.y * 128;
    int lane = t & 63, wave = t >> 6;
    int wr = wave >> 1, wc = wave & 1;
    int quad = lane >> 4, lm = lane & 15;
    f32x4 acc[4][4] = {};   // acc[j][i]: C^T fragment. n = quad*4+reg dim, m = lm dim

    // staging: 1024 chunks of 8 bf16 per matrix, 4 passes x 256 threads
    const bf16* gA[4]; const bf16* gB[4];
    bf16 *lA[4], *lB[4];
    #pragma unroll
    for (int p = 0; p < 4; p++) {
        int c = p * 256 + t;
        int row = c >> 3, g = c & 7;
        int gs = g ^ (row & 7);                 // inverse swizzle on the SOURCE
        gA[p] = A  + (size_t)(m0 + row) * Kdim + gs * 8;
        gB[p] = Wt + (size_t)(n0 + row) * Kdim + gs * 8;
        lA[p] = As + c * 8;                     // linear LDS dest (wave-uniform + lane*16)
        lB[p] = Bs + c * 8;
    }

    for (int k0 = 0; k0 < Kdim; k0 += 64) {
        #pragma unroll
        for (int p = 0; p < 4; p++) {
            gld_lds16(gA[p] + k0, lA[p]);
            gld_lds16(gB[p] + k0, lB[p]);
        }
        __syncthreads();
        #pragma unroll
        for (int kk = 0; kk < 2; kk++) {
            bf16x8 af[4], bfr[4];
            int grp = (kk * 4 + quad) ^ (lm & 7);   // swizzled read group
            #pragma unroll
            for (int i = 0; i < 4; i++)
                af[i] = *(const bf16x8*)(As + (wr * 64 + i * 16 + lm) * 64 + grp * 8);
            #pragma unroll
            for (int j = 0; j < 4; j++)
                bfr[j] = *(const bf16x8*)(Bs + (wc * 64 + j * 16 + lm) * 64 + grp * 8);
            #pragma unroll
            for (int j = 0; j < 4; j++)
                #pragma unroll
                for (int i = 0; i < 4; i++)
                    acc[j][i] = __builtin_amdgcn_mfma_f32_16x16x32_bf16(bfr[j], af[i], acc[j][i], 0, 0, 0);
        }
        __syncthreads();
    }

    // ---- epilogue (transposed fragments): m = m0+wr*64+i*16+lm ; n = n0+wc*64+j*16+quad*4+r
    #pragma unroll
    for (int i = 0; i < 4; i++) {
        int m = m0 + wr * 64 + i * 16 + lm;
        size_t resbase = 0;
        if (EPI == EPI_PROJ) {
            int wi = m / 49, n_ = m % 49;
            int b = wi >> 6, w64 = wi & 63;
            int bh = w64 >> 3, bw = w64 & 7;
            int hs = bh * 7 + n_ / 7 + 3; if (hs >= 56) hs -= 56;
            int wsd = bw * 7 + n_ % 7 + 3; if (wsd >= 56) wsd -= 56;
            resbase = (size_t)b * C_ * 3136 + hs * 56 + wsd;
        }
        #pragma unroll
        for (int j = 0; j < 4; j++) {
            int nb = n0 + wc * 64 + j * 16 + quad * 4;
            f32x4 bj = *(const f32x4*)(bias + nb);
            f32x4 v;
            #pragma unroll
            for (int r = 0; r < 4; r++) v[r] = acc[j][i][r] + bj[r];
            if (EPI == EPI_GELU) {
                #pragma unroll
                for (int r = 0; r < 4; r++) v[r] = fast_gelu(v[r]);
            }
            if (EPI == EPI_PROJ) {
                #pragma unroll
                for (int r = 0; r < 4; r++) v[r] += resx[resbase + (size_t)(nb + r) * 3136];
            }
            if (EPI == EPI_FC2) {
                bf16x4 rb = *(const bf16x4*)(resb + (size_t)m * 384 + nb);
                #pragma unroll
                for (int r = 0; r < 4; r++) v[r] += b2f(rb[r]);
            }
            bf16x4 o;
            #pragma unroll
            for (int r = 0; r < 4; r++) o[r] = f2b(v[r]);
            *(bf16x4*)(Cout + (size_t)m * Ndim + nb) = o;
        }
    }
}

// ---------- K3: MFMA windowed attention. one wave-block per (window, head) ----------
__global__ __launch_bounds__(64) void attn_mfma_kernel(const bf16* __restrict__ qkv,
                                                       bf16* __restrict__ aout) {
    __shared__ __align__(16) bf16 pbuf[64 * 72];
    __shared__ int reg_[64];
    int l = threadIdx.x;
    int wi = blockIdx.x / 12, h = blockIdx.x % 12;
    int i16 = l & 15, quad = l >> 4;

    {
        int tok = l < 49 ? l : 48;
        int w64 = wi & 63;
        int bh = w64 >> 3, bw = w64 & 7;
        int hh = bh * 7 + tok / 7, ww = bw * 7 + tok % 7;
        int fh = hh < 49 ? 0 : (hh < 53 ? 1 : 2);
        int fw = ww < 49 ? 0 : (ww < 53 ? 1 : 2);
        reg_[l] = fh * 3 + fw;
    }
    __syncthreads();

    const bf16* qbase = qkv + (size_t)wi * 49 * 1152 + h * 32;

    // ---- S = Q @ K^T ----
    f32x4 s_[4][4] = {};   // [mi][nt], C-layout
    bf16x8 af[4], bfr[4];
    #pragma unroll
    for (int mi = 0; mi < 4; mi++) {
        int m = mi * 16 + i16; if (m > 48) m = 48;
        af[mi] = *(const bf16x8*)(qbase + (size_t)m * 1152 + quad * 8);
    }
    #pragma unroll
    for (int nt = 0; nt < 4; nt++) {
        int n = nt * 16 + i16; if (n > 48) n = 48;
        bfr[nt] = *(const bf16x8*)(qbase + 384 + (size_t)n * 1152 + quad * 8);
    }
    #pragma unroll
    for (int mi = 0; mi < 4; mi++)
        #pragma unroll
        for (int nt = 0; nt < 4; nt++)
            s_[mi][nt] = __builtin_amdgcn_mfma_f32_16x16x32_bf16(af[mi], bfr[nt], s_[mi][nt], 0, 0, 0);

    int creg[4];
    #pragma unroll
    for (int nt = 0; nt < 4; nt++) {
        int c = nt * 16 + i16; if (c > 48) c = 48;
        creg[nt] = reg_[c];
    }

    // ---- mask + softmax ----
    const float scale = 0.17677669529663687f;  // 1/sqrt(32)
    #pragma unroll
    for (int mi = 0; mi < 4; mi++) {
        #pragma unroll
        for (int r = 0; r < 4; r++) {
            int row = mi * 16 + quad * 4 + r;
            int rreg = reg_[row];
            float v[4]; float mx = -1e30f;
            #pragma unroll
            for (int nt = 0; nt < 4; nt++) {
                int c = nt * 16 + i16;
                float x = s_[mi][nt][r] * scale;
                if (c > 48) x = -1e30f;
                else if (rreg != creg[nt]) x -= 100.0f;
                v[nt] = x; mx = fmaxf(mx, x);
            }
            #pragma unroll
            for (int m = 8; m; m >>= 1) mx = fmaxf(mx, __shfl_xor(mx, m));
            float sum = 0.f;
            #pragma unroll
            for (int nt = 0; nt < 4; nt++) { v[nt] = __expf(v[nt] - mx); sum += v[nt]; }
            #pragma unroll
            for (int m = 8; m; m >>= 1) sum += __shfl_xor(sum, m);
            float inv = 1.0f / sum;
            #pragma unroll
            for (int nt = 0; nt < 4; nt++)
                pbuf[row * 72 + nt * 16 + i16] = f2b(v[nt] * inv);
        }
    }
    __syncthreads();

    // ---- O = P @ V ----
    f32x4 o_[4][2] = {};
    const bf16* vbase = qkv + (size_t)wi * 49 * 1152 + 768 + h * 32;
    #pragma unroll
    for (int ks = 0; ks < 2; ks++) {
        bf16x8 pa[4];
        #pragma unroll
        for (int mi = 0; mi < 4; mi++)
            pa[mi] = *(const bf16x8*)(pbuf + (mi * 16 + i16) * 72 + ks * 32 + quad * 8);
        bf16x8 vb[2];
        #pragma unroll
        for (int nt = 0; nt < 2; nt++)
            #pragma unroll
            for (int j = 0; j < 8; j++) {
                int tok = ks * 32 + quad * 8 + j; if (tok > 48) tok = 48;
                vb[nt][j] = vbase[(size_t)tok * 1152 + nt * 16 + i16];
            }
        #pragma unroll
        for (int mi = 0; mi < 4; mi++)
            #pragma unroll
            for (int nt = 0; nt < 2; nt++)
                o_[mi][nt] = __builtin_amdgcn_mfma_f32_16x16x32_bf16(pa[mi], vb[nt], o_[mi][nt], 0, 0, 0);
    }

    // ---- epilogue: write rows < 49 ----
    bf16* obase = aout + (size_t)wi * 49 * 384 + h * 32;
    #pragma unroll
    for (int mi = 0; mi < 4; mi++)
        #pragma unroll
        for (int r = 0; r < 4; r++) {
            int row = mi * 16 + quad * 4 + r;
            if (row < 49) {
                #pragma unroll
                for (int nt = 0; nt < 2; nt++)
                    obase[(size_t)row * 384 + nt * 16 + i16] = f2b(o_[mi][nt][r]);
            }
        }
}

// ---------- K5: LN2 on token-major bf16 ----------
__global__ __launch_bounds__(256) void ln2_kernel(const bf16* __restrict__ x2,
                                                  const float* __restrict__ g,
                                                  const float* __restrict__ bt,
                                                  bf16* __restrict__ x2n) {
    int wave = threadIdx.x >> 6, lane = threadIdx.x & 63;
    int T = blockIdx.x * 4 + wave;
    const bf16* xp = x2 + (size_t)T * 384;
    float v[6];
    #pragma unroll
    for (int k = 0; k < 6; k++) v[k] = b2f(xp[lane + k * 64]);
    float s = v[0] + v[1] + v[2] + v[3] + v[4] + v[5];
    #pragma unroll
    for (int m = 32; m; m >>= 1) s += __shfl_xor(s, m);
    float mu = s * (1.0f / 384.0f);
    float s2 = 0.f;
    #pragma unroll
    for (int k = 0; k < 6; k++) { float d = v[k] - mu; s2 += d * d; }
    #pragma unroll
    for (int m = 32; m; m >>= 1) s2 += __shfl_xor(s2, m);
    float rstd = rsqrtf(s2 * (1.0f / 384.0f) + 1e-5f);
    bf16* op = x2n + (size_t)T * 384;
    #pragma unroll
    for (int k = 0; k < 6; k++) {
        int c = lane + k * 64;
        op[c] = f2b((v[k] - mu) * rstd * g[c] + bt[c]);
    }
}

// ---------- K8: window reverse + unshift + transpose to BCHW f32 ----------
__global__ __launch_bounds__(256) void untile_kernel(const bf16* __restrict__ otok,
                                                     float* __restrict__ out) {
    __shared__ float tile[56 * 65];
    int t = threadIdx.x;
    int b = blockIdx.x / 336;       // 56*6
    int rem = blockIdx.x % 336;
    int h = rem / 6;
    int c0 = (rem % 6) * 64;
    int hs = h + 53; if (hs >= 56) hs -= 56;
    int bh = hs / 7, th = hs % 7;
    #pragma unroll
    for (int pass = 0; pass < 14; pass++) {
        int w = pass * 4 + (t >> 6);
        int c = t & 63;
        int wsd = w + 53; if (wsd >= 56) wsd -= 56;
        int T = (b * 64 + bh * 8 + wsd / 7) * 49 + th * 7 + wsd % 7;
        tile[w * 65 + c] = b2f(otok[(size_t)T * 384 + c0 + c]);
    }
    __syncthreads();
    #pragma unroll
    for (int pass = 0; pass < 14; pass++) {
        int idx = pass * 256 + t;
        int c = idx / 56, w = idx % 56;
        out[((size_t)(b * 384 + c0 + c)) * 3136 + h * 56 + w] = tile[w * 65 + c];
    }
}

// ---------- launcher ----------
extern "C" void kernel_launch(void* const* d_in, const int* in_sizes, int n_in,
                              void* d_out, int out_size, void* d_ws, size_t ws_size,
                              hipStream_t stream) {
    (void)in_sizes; (void)n_in; (void)out_size; (void)ws_size;
    const float* x      = (const float*)d_in[0];
    const float* n1g    = (const float*)d_in[1];
    const float* n1b    = (const float*)d_in[2];
    const float* qkv_w  = (const float*)d_in[3];
    const float* qkv_b  = (const float*)d_in[4];
    const float* proj_w = (const float*)d_in[5];
    const float* proj_b = (const float*)d_in[6];
    const float* n2g    = (const float*)d_in[7];
    const float* n2b    = (const float*)d_in[8];
    const float* fc1_w  = (const float*)d_in[9];
    const float* fc1_b  = (const float*)d_in[10];
    const float* fc2_w  = (const float*)d_in[11];
    const float* fc2_b  = (const float*)d_in[12];
    float* out = (float*)d_out;
    char* ws = (char*)d_ws;

    bf16* qkv_wT = (bf16*)(ws + 0);          // 884736 B
    bf16* proj_wT = (bf16*)(ws + 884736);    // 294912 B
    bf16* fc1_wT = (bf16*)(ws + 1179648);    // 1179648 B
    bf16* fc2_wT = (bf16*)(ws + 2359296);    // 1179648 B
    bf16* xw   = (bf16*)(ws + 4194304);      // 38535168 B
    bf16* qkvb = (bf16*)(ws + 42729472);     // 115605504 B
    bf16* attn = (bf16*)(ws + 158334976);    // 38535168 B
    bf16* x2   = (bf16*)(ws + 4194304);      // alias xw (dead)
    bf16* x2n  = (bf16*)(ws + 42729472);     // alias qkv (dead)
    bf16* h1   = (bf16*)(ws + 81264640);     // 154140672 B (overlaps dead attn)
    bf16* otok = (bf16*)(ws + 235405312);    // 38535168 B  (peak ws = 274 MB)

    wtrans_kernel<<<(384 * 1152 + 255) / 256, 256, 0, stream>>>(qkv_w, qkv_wT, 384, 1152);
    wtrans_kernel<<<(384 * 384 + 255) / 256, 256, 0, stream>>>(proj_w, proj_wT, 384, 384);
    wtrans_kernel<<<(384 * 1536 + 255) / 256, 256, 0, stream>>>(fc1_w, fc1_wT, 384, 1536);
    wtrans_kernel<<<(1536 * 384 + 255) / 256, 256, 0, stream>>>(fc2_w, fc2_wT, 1536, 384);

    ln1_gather_kernel<<<TOKENS / 4, 256, 0, stream>>>(x, n1g, n1b, xw);

    gemm_kernel<EPI_NONE><<<dim3(392, 9), 256, 0, stream>>>(
        xw, qkv_wT, qkv_b, qkvb, 384, 1152, nullptr, nullptr);

    attn_mfma_kernel<<<12288, 64, 0, stream>>>(qkvb, attn);

    gemm_kernel<EPI_PROJ><<<dim3(392, 3), 256, 0, stream>>>(
        attn, proj_wT, proj_b, x2, 384, 384, x, nullptr);

    ln2_kernel<<<TOKENS / 4, 256, 0, stream>>>(x2, n2g, n2b, x2n);

    gemm_kernel<EPI_GELU><<<dim3(392, 12), 256, 0, stream>>>(
        x2n, fc1_wT, fc1_b, h1, 384, 1536, nullptr, nullptr);

    gemm_kernel<EPI_FC2><<<dim3(392, 3), 256, 0, stream>>>(
        h1, fc2_wT, fc2_b, otok, 1536, 384, nullptr, x2);

    untile_kernel<<<16 * 336, 256, 0, stream>>>(otok, out);
}

// Round 2
// 715.804 us; speedup vs baseline: 1.0322x; 1.0285x over previous
//
#include <hip/hip_runtime.h>
#include <hip/hip_bf16.h>
#include <math.h>
#include <stdint.h>

// ---------- constants ----------
#define C_ 384
#define TOKENS 50176          // B*H*W = 16*56*56 = 16*64*49

typedef __bf16 bf16;
typedef __bf16 bf16x8 __attribute__((ext_vector_type(8)));
typedef __bf16 bf16x4 __attribute__((ext_vector_type(4)));
typedef float  f32x4  __attribute__((ext_vector_type(4)));

__device__ __forceinline__ float b2f(bf16 x) { return (float)x; }
__device__ __forceinline__ bf16  f2b(float x) { return (bf16)x; }

// tanh-form GELU: v * sigmoid(1.5957691 v + 0.0713548 v^3)
__device__ __forceinline__ float fast_gelu(float v) {
    float u2 = v * fmaf(v * v, 0.07135481f, 1.5957691f);
    return v / (1.0f + __expf(-u2));
}

// async global->LDS, 16 bytes per lane. LDS dest must be wave-uniform base + lane*16.
__device__ __forceinline__ void gld_lds16(const bf16* g, bf16* l) {
    __builtin_amdgcn_global_load_lds(
        (const __attribute__((address_space(1))) void*)g,
        (__attribute__((address_space(3))) void*)l, 16, 0, 0);
}

// ---------- K0: weight convert+transpose: in f32 [K][N] -> out bf16 [N][K] ----------
__global__ void wtrans_kernel(const float* __restrict__ in, bf16* __restrict__ out,
                              int K, int N) {
    int idx = blockIdx.x * 256 + threadIdx.x;
    if (idx >= K * N) return;
    int n = idx / K, k = idx % K;
    out[idx] = f2b(in[(size_t)k * N + n]);
}

// ---------- K1: LN1 + roll(-3,-3) + window partition. x BCHW f32 -> xw [50176][384] bf16 ----------
__global__ __launch_bounds__(256) void ln1_gather_kernel(
    const float* __restrict__ x, const float* __restrict__ g,
    const float* __restrict__ bt, bf16* __restrict__ xw) {
    int wave = threadIdx.x >> 6, lane = threadIdx.x & 63;
    int T = blockIdx.x * 4 + wave;
    int wi = T / 49, n = T % 49;
    int b = wi >> 6, w64 = wi & 63;
    int bh = w64 >> 3, bw = w64 & 7;
    int hs = bh * 7 + n / 7 + 3; if (hs >= 56) hs -= 56;
    int wsd = bw * 7 + n % 7 + 3; if (wsd >= 56) wsd -= 56;
    const float* xp = x + (size_t)b * C_ * 3136 + hs * 56 + wsd;
    float v[6];
    #pragma unroll
    for (int k = 0; k < 6; k++) v[k] = xp[(size_t)(lane + k * 64) * 3136];
    float s = v[0] + v[1] + v[2] + v[3] + v[4] + v[5];
    #pragma unroll
    for (int m = 32; m; m >>= 1) s += __shfl_xor(s, m);
    float mu = s * (1.0f / 384.0f);
    float s2 = 0.f;
    #pragma unroll
    for (int k = 0; k < 6; k++) { float d = v[k] - mu; s2 += d * d; }
    #pragma unroll
    for (int m = 32; m; m >>= 1) s2 += __shfl_xor(s2, m);
    float rstd = rsqrtf(s2 * (1.0f / 384.0f) + 1e-5f);
    bf16* op = xw + (size_t)T * 384;
    #pragma unroll
    for (int k = 0; k < 6; k++) {
        int c = lane + k * 64;
        op[c] = f2b((v[k] - mu) * rstd * g[c] + bt[c]);
    }
}

// ---------- GEMM: C[M][N] = A[M][K] @ Wt[N][K]^T + bias ----------
// 128x128 tile, BK=32, DOUBLE-BUFFERED 2-phase prefetch: one __syncthreads per
// K-step, placed so the compiler's vmcnt(0) drain happens AFTER the compute phase
// that overlaps the in-flight next-tile loads (T3-minimum).
// Grid is n-INNER (blockIdx.x = n-block) + XCD-chunked bijective remap (m204):
// consecutive logical blocks share the A row-panel and land on the same XCD L2.
// LDS swizzle: group g at row r holds global group g^((r>>1)&3); every
// consecutive 8-lane ds_read_b128 group hits 8 distinct 16B granules (0-conflict).
enum { EPI_NONE = 0, EPI_GELU = 1, EPI_PROJ = 2, EPI_FC2 = 3 };

template <int EPI>
__global__ __launch_bounds__(256) void gemm_kernel(
    const bf16* __restrict__ A, const bf16* __restrict__ Wt,
    const float* __restrict__ bias, bf16* __restrict__ Cout,
    int Kdim, int Ndim,
    const float* __restrict__ resx,   // EPI_PROJ: x in BCHW f32
    const bf16* __restrict__ resb) {  // EPI_FC2 : x2 token-major bf16
    __shared__ __align__(16) bf16 As[2][128 * 32];
    __shared__ __align__(16) bf16 Bs[2][128 * 32];
    int t = threadIdx.x;

    // n-inner linear order + XCD-chunked bijective remap
    int nwg = gridDim.x * gridDim.y;
    int bid = blockIdx.y * gridDim.x + blockIdx.x;
    int q8 = nwg >> 3, r8 = nwg & 7, xcd = bid & 7, off = bid >> 3;
    int swz = (xcd < r8 ? xcd * (q8 + 1) : r8 * (q8 + 1) + (xcd - r8) * q8) + off;
    int n0 = (swz % gridDim.x) * 128;
    int m0 = (swz / gridDim.x) * 128;

    int lane = t & 63, wave = t >> 6;
    int wr = wave >> 1, wc = wave & 1;
    int quad = lane >> 4, lm = lane & 15;
    f32x4 acc[4][4] = {};   // acc[j][i]: C^T fragment. n = quad*4+reg dim, m = lm dim

    // staging: 512 chunks of 8 bf16 per matrix, 2 passes x 256 threads
    const bf16* gA[2]; const bf16* gB[2];
    int lofs[2];
    #pragma unroll
    for (int p = 0; p < 2; p++) {
        int c = p * 256 + t;
        int row = c >> 2, g = c & 3;
        int gs = g ^ ((row >> 1) & 3);          // inverse swizzle on the SOURCE
        gA[p] = A  + (size_t)(m0 + row) * Kdim + gs * 8;
        gB[p] = Wt + (size_t)(n0 + row) * Kdim + gs * 8;
        lofs[p] = c * 8;                        // linear LDS dest (uniform + lane*16)
    }
    int grp = quad ^ ((lm >> 1) & 3);           // swizzled read group (uniform/thread)

    int nt = Kdim >> 5;
    int cur = 0;
    // prologue: stage tile 0
    #pragma unroll
    for (int p = 0; p < 2; p++) {
        gld_lds16(gA[p], &As[0][lofs[p]]);
        gld_lds16(gB[p], &Bs[0][lofs[p]]);
    }
    for (int tk = 0; tk < nt; ++tk) {
        __syncthreads();                        // drains loads for buf[cur] (in flight
                                                // during previous compute phase)
        if (tk + 1 < nt) {                      // issue next-tile loads -> overlap
            int k0 = (tk + 1) << 5;
            #pragma unroll
            for (int p = 0; p < 2; p++) {
                gld_lds16(gA[p] + k0, &As[cur ^ 1][lofs[p]]);
                gld_lds16(gB[p] + k0, &Bs[cur ^ 1][lofs[p]]);
            }
        }
        bf16x8 af[4], bfr[4];
        #pragma unroll
        for (int i = 0; i < 4; i++)
            af[i] = *(const bf16x8*)(&As[cur][(wr * 64 + i * 16 + lm) * 32 + grp * 8]);
        #pragma unroll
        for (int j = 0; j < 4; j++)
            bfr[j] = *(const bf16x8*)(&Bs[cur][(wc * 64 + j * 16 + lm) * 32 + grp * 8]);
        #pragma unroll
        for (int j = 0; j < 4; j++)
            #pragma unroll
            for (int i = 0; i < 4; i++)
                acc[j][i] = __builtin_amdgcn_mfma_f32_16x16x32_bf16(bfr[j], af[i], acc[j][i], 0, 0, 0);
        cur ^= 1;
    }

    // ---- epilogue (transposed fragments): m = m0+wr*64+i*16+lm ; n = n0+wc*64+j*16+quad*4+r
    #pragma unroll
    for (int i = 0; i < 4; i++) {
        int m = m0 + wr * 64 + i * 16 + lm;
        size_t resbase = 0;
        if (EPI == EPI_PROJ) {
            int wi = m / 49, n_ = m % 49;
            int b = wi >> 6, w64 = wi & 63;
            int bh = w64 >> 3, bw = w64 & 7;
            int hs = bh * 7 + n_ / 7 + 3; if (hs >= 56) hs -= 56;
            int wsd = bw * 7 + n_ % 7 + 3; if (wsd >= 56) wsd -= 56;
            resbase = (size_t)b * C_ * 3136 + hs * 56 + wsd;
        }
        #pragma unroll
        for (int j = 0; j < 4; j++) {
            int nb = n0 + wc * 64 + j * 16 + quad * 4;
            f32x4 bj = *(const f32x4*)(bias + nb);
            f32x4 v;
            #pragma unroll
            for (int r = 0; r < 4; r++) v[r] = acc[j][i][r] + bj[r];
            if (EPI == EPI_GELU) {
                #pragma unroll
                for (int r = 0; r < 4; r++) v[r] = fast_gelu(v[r]);
            }
            if (EPI == EPI_PROJ) {
                #pragma unroll
                for (int r = 0; r < 4; r++) v[r] += resx[resbase + (size_t)(nb + r) * 3136];
            }
            if (EPI == EPI_FC2) {
                bf16x4 rb = *(const bf16x4*)(resb + (size_t)m * 384 + nb);
                #pragma unroll
                for (int r = 0; r < 4; r++) v[r] += b2f(rb[r]);
            }
            bf16x4 o;
            #pragma unroll
            for (int r = 0; r < 4; r++) o[r] = f2b(v[r]);
            *(bf16x4*)(Cout + (size_t)m * Ndim + nb) = o;
        }
    }
}

// ---------- K3: MFMA windowed attention. one wave-block per (window, head) ----------
__global__ __launch_bounds__(64) void attn_mfma_kernel(const bf16* __restrict__ qkv,
                                                       bf16* __restrict__ aout) {
    __shared__ __align__(16) bf16 pbuf[64 * 72];
    __shared__ int reg_[64];
    int l = threadIdx.x;
    int wi = blockIdx.x / 12, h = blockIdx.x % 12;
    int i16 = l & 15, quad = l >> 4;

    {
        int tok = l < 49 ? l : 48;
        int w64 = wi & 63;
        int bh = w64 >> 3, bw = w64 & 7;
        int hh = bh * 7 + tok / 7, ww = bw * 7 + tok % 7;
        int fh = hh < 49 ? 0 : (hh < 53 ? 1 : 2);
        int fw = ww < 49 ? 0 : (ww < 53 ? 1 : 2);
        reg_[l] = fh * 3 + fw;
    }
    __syncthreads();

    const bf16* qbase = qkv + (size_t)wi * 49 * 1152 + h * 32;

    // ---- S = Q @ K^T ----
    f32x4 s_[4][4] = {};   // [mi][nt], C-layout
    bf16x8 af[4], bfr[4];
    #pragma unroll
    for (int mi = 0; mi < 4; mi++) {
        int m = mi * 16 + i16; if (m > 48) m = 48;
        af[mi] = *(const bf16x8*)(qbase + (size_t)m * 1152 + quad * 8);
    }
    #pragma unroll
    for (int nt = 0; nt < 4; nt++) {
        int n = nt * 16 + i16; if (n > 48) n = 48;
        bfr[nt] = *(const bf16x8*)(qbase + 384 + (size_t)n * 1152 + quad * 8);
    }
    #pragma unroll
    for (int mi = 0; mi < 4; mi++)
        #pragma unroll
        for (int nt = 0; nt < 4; nt++)
            s_[mi][nt] = __builtin_amdgcn_mfma_f32_16x16x32_bf16(af[mi], bfr[nt], s_[mi][nt], 0, 0, 0);

    int creg[4];
    #pragma unroll
    for (int nt = 0; nt < 4; nt++) {
        int c = nt * 16 + i16; if (c > 48) c = 48;
        creg[nt] = reg_[c];
    }

    // ---- mask + softmax ----
    const float scale = 0.17677669529663687f;  // 1/sqrt(32)
    #pragma unroll
    for (int mi = 0; mi < 4; mi++) {
        #pragma unroll
        for (int r = 0; r < 4; r++) {
            int row = mi * 16 + quad * 4 + r;
            int rreg = reg_[row];
            float v[4]; float mx = -1e30f;
            #pragma unroll
            for (int nt = 0; nt < 4; nt++) {
                int c = nt * 16 + i16;
                float x = s_[mi][nt][r] * scale;
                if (c > 48) x = -1e30f;
                else if (rreg != creg[nt]) x -= 100.0f;
                v[nt] = x; mx = fmaxf(mx, x);
            }
            #pragma unroll
            for (int m = 8; m; m >>= 1) mx = fmaxf(mx, __shfl_xor(mx, m));
            float sum = 0.f;
            #pragma unroll
            for (int nt = 0; nt < 4; nt++) { v[nt] = __expf(v[nt] - mx); sum += v[nt]; }
            #pragma unroll
            for (int m = 8; m; m >>= 1) sum += __shfl_xor(sum, m);
            float inv = 1.0f / sum;
            #pragma unroll
            for (int nt = 0; nt < 4; nt++)
                pbuf[row * 72 + nt * 16 + i16] = f2b(v[nt] * inv);
        }
    }
    __syncthreads();

    // ---- O = P @ V ----
    f32x4 o_[4][2] = {};
    const bf16* vbase = qkv + (size_t)wi * 49 * 1152 + 768 + h * 32;
    #pragma unroll
    for (int ks = 0; ks < 2; ks++) {
        bf16x8 pa[4];
        #pragma unroll
        for (int mi = 0; mi < 4; mi++)
            pa[mi] = *(const bf16x8*)(pbuf + (mi * 16 + i16) * 72 + ks * 32 + quad * 8);
        bf16x8 vb[2];
        #pragma unroll
        for (int nt = 0; nt < 2; nt++)
            #pragma unroll
            for (int j = 0; j < 8; j++) {
                int tok = ks * 32 + quad * 8 + j; if (tok > 48) tok = 48;
                vb[nt][j] = vbase[(size_t)tok * 1152 + nt * 16 + i16];
            }
        #pragma unroll
        for (int mi = 0; mi < 4; mi++)
            #pragma unroll
            for (int nt = 0; nt < 2; nt++)
                o_[mi][nt] = __builtin_amdgcn_mfma_f32_16x16x32_bf16(pa[mi], vb[nt], o_[mi][nt], 0, 0, 0);
    }

    // ---- epilogue: write rows < 49 ----
    bf16* obase = aout + (size_t)wi * 49 * 384 + h * 32;
    #pragma unroll
    for (int mi = 0; mi < 4; mi++)
        #pragma unroll
        for (int r = 0; r < 4; r++) {
            int row = mi * 16 + quad * 4 + r;
            if (row < 49) {
                #pragma unroll
                for (int nt = 0; nt < 2; nt++)
                    obase[(size_t)row * 384 + nt * 16 + i16] = f2b(o_[mi][nt][r]);
            }
        }
}

// ---------- K5: LN2 on token-major bf16 ----------
__global__ __launch_bounds__(256) void ln2_kernel(const bf16* __restrict__ x2,
                                                  const float* __restrict__ g,
                                                  const float* __restrict__ bt,
                                                  bf16* __restrict__ x2n) {
    int wave = threadIdx.x >> 6, lane = threadIdx.x & 63;
    int T = blockIdx.x * 4 + wave;
    const bf16* xp = x2 + (size_t)T * 384;
    float v[6];
    #pragma unroll
    for (int k = 0; k < 6; k++) v[k] = b2f(xp[lane + k * 64]);
    float s = v[0] + v[1] + v[2] + v[3] + v[4] + v[5];
    #pragma unroll
    for (int m = 32; m; m >>= 1) s += __shfl_xor(s, m);
    float mu = s * (1.0f / 384.0f);
    float s2 = 0.f;
    #pragma unroll
    for (int k = 0; k < 6; k++) { float d = v[k] - mu; s2 += d * d; }
    #pragma unroll
    for (int m = 32; m; m >>= 1) s2 += __shfl_xor(s2, m);
    float rstd = rsqrtf(s2 * (1.0f / 384.0f) + 1e-5f);
    bf16* op = x2n + (size_t)T * 384;
    #pragma unroll
    for (int k = 0; k < 6; k++) {
        int c = lane + k * 64;
        op[c] = f2b((v[k] - mu) * rstd * g[c] + bt[c]);
    }
}

// ---------- K8: window reverse + unshift + transpose to BCHW f32 ----------
__global__ __launch_bounds__(256) void untile_kernel(const bf16* __restrict__ otok,
                                                     float* __restrict__ out) {
    __shared__ float tile[56 * 65];
    int t = threadIdx.x;
    int b = blockIdx.x / 336;       // 56*6
    int rem = blockIdx.x % 336;
    int h = rem / 6;
    int c0 = (rem % 6) * 64;
    int hs = h + 53; if (hs >= 56) hs -= 56;
    int bh = hs / 7, th = hs % 7;
    #pragma unroll
    for (int pass = 0; pass < 14; pass++) {
        int w = pass * 4 + (t >> 6);
        int c = t & 63;
        int wsd = w + 53; if (wsd >= 56) wsd -= 56;
        int T = (b * 64 + bh * 8 + wsd / 7) * 49 + th * 7 + wsd % 7;
        tile[w * 65 + c] = b2f(otok[(size_t)T * 384 + c0 + c]);
    }
    __syncthreads();
    #pragma unroll
    for (int pass = 0; pass < 14; pass++) {
        int idx = pass * 256 + t;
        int c = idx / 56, w = idx % 56;
        out[((size_t)(b * 384 + c0 + c)) * 3136 + h * 56 + w] = tile[w * 65 + c];
    }
}

// ---------- launcher ----------
extern "C" void kernel_launch(void* const* d_in, const int* in_sizes, int n_in,
                              void* d_out, int out_size, void* d_ws, size_t ws_size,
                              hipStream_t stream) {
    (void)in_sizes; (void)n_in; (void)out_size; (void)ws_size;
    const float* x      = (const float*)d_in[0];
    const float* n1g    = (const float*)d_in[1];
    const float* n1b    = (const float*)d_in[2];
    const float* qkv_w  = (const float*)d_in[3];
    const float* qkv_b  = (const float*)d_in[4];
    const float* proj_w = (const float*)d_in[5];
    const float* proj_b = (const float*)d_in[6];
    const float* n2g    = (const float*)d_in[7];
    const float* n2b    = (const float*)d_in[8];
    const float* fc1_w  = (const float*)d_in[9];
    const float* fc1_b  = (const float*)d_in[10];
    const float* fc2_w  = (const float*)d_in[11];
    const float* fc2_b  = (const float*)d_in[12];
    float* out = (float*)d_out;
    char* ws = (char*)d_ws;

    bf16* qkv_wT = (bf16*)(ws + 0);          // 884736 B
    bf16* proj_wT = (bf16*)(ws + 884736);    // 294912 B
    bf16* fc1_wT = (bf16*)(ws + 1179648);    // 1179648 B
    bf16* fc2_wT = (bf16*)(ws + 2359296);    // 1179648 B
    bf16* xw   = (bf16*)(ws + 4194304);      // 38535168 B
    bf16* qkvb = (bf16*)(ws + 42729472);     // 115605504 B
    bf16* attn = (bf16*)(ws + 158334976);    // 38535168 B
    bf16* x2   = (bf16*)(ws + 4194304);      // alias xw (dead)
    bf16* x2n  = (bf16*)(ws + 42729472);     // alias qkv (dead)
    bf16* h1   = (bf16*)(ws + 81264640);     // 154140672 B (overlaps dead attn)
    bf16* otok = (bf16*)(ws + 235405312);    // 38535168 B  (peak ws = 274 MB)

    wtrans_kernel<<<(384 * 1152 + 255) / 256, 256, 0, stream>>>(qkv_w, qkv_wT, 384, 1152);
    wtrans_kernel<<<(384 * 384 + 255) / 256, 256, 0, stream>>>(proj_w, proj_wT, 384, 384);
    wtrans_kernel<<<(384 * 1536 + 255) / 256, 256, 0, stream>>>(fc1_w, fc1_wT, 384, 1536);
    wtrans_kernel<<<(1536 * 384 + 255) / 256, 256, 0, stream>>>(fc2_w, fc2_wT, 1536, 384);

    ln1_gather_kernel<<<TOKENS / 4, 256, 0, stream>>>(x, n1g, n1b, xw);

    // n-INNER grids: blockIdx.x = n-block, blockIdx.y = m-panel
    gemm_kernel<EPI_NONE><<<dim3(9, 392), 256, 0, stream>>>(
        xw, qkv_wT, qkv_b, qkvb, 384, 1152, nullptr, nullptr);

    attn_mfma_kernel<<<12288, 64, 0, stream>>>(qkvb, attn);

    gemm_kernel<EPI_PROJ><<<dim3(3, 392), 256, 0, stream>>>(
        attn, proj_wT, proj_b, x2, 384, 384, x, nullptr);

    ln2_kernel<<<TOKENS / 4, 256, 0, stream>>>(x2, n2g, n2b, x2n);

    gemm_kernel<EPI_GELU><<<dim3(12, 392), 256, 0, stream>>>(
        x2n, fc1_wT, fc1_b, h1, 384, 1536, nullptr, nullptr);

    gemm_kernel<EPI_FC2><<<dim3(3, 392), 256, 0, stream>>>(
        h1, fc2_wT, fc2_b, otok, 1536, 384, nullptr, x2);

    untile_kernel<<<16 * 336, 256, 0, stream>>>(otok, out);
}

// Round 3
// 701.709 us; speedup vs baseline: 1.0529x; 1.0201x over previous
//
#include <hip/hip_runtime.h>
#include <hip/hip_bf16.h>
#include <math.h>
#include <stdint.h>

// ---------- constants ----------
#define C_ 384
#define TOKENS 50176          // B*H*W = 16*56*56 = 16*64*49

typedef __bf16 bf16;
typedef __bf16 bf16x8 __attribute__((ext_vector_type(8)));
typedef __bf16 bf16x4 __attribute__((ext_vector_type(4)));
typedef float  f32x4  __attribute__((ext_vector_type(4)));

__device__ __forceinline__ float b2f(bf16 x) { return (float)x; }
__device__ __forceinline__ bf16  f2b(float x) { return (bf16)x; }

// tanh-form GELU: v * sigmoid(1.5957691 v + 0.0713548 v^3)
__device__ __forceinline__ float fast_gelu(float v) {
    float u2 = v * fmaf(v * v, 0.07135481f, 1.5957691f);
    return v / (1.0f + __expf(-u2));
}

// async global->LDS, 16 bytes per lane. LDS dest must be wave-uniform base + lane*16.
__device__ __forceinline__ void gld_lds16(const bf16* g, bf16* l) {
    __builtin_amdgcn_global_load_lds(
        (const __attribute__((address_space(1))) void*)g,
        (__attribute__((address_space(3))) void*)l, 16, 0, 0);
}

// ---------- K0: weight convert+transpose: in f32 [K][N] -> out bf16 [N][K] ----------
__global__ void wtrans_kernel(const float* __restrict__ in, bf16* __restrict__ out,
                              int K, int N) {
    int idx = blockIdx.x * 256 + threadIdx.x;
    if (idx >= K * N) return;
    int n = idx / K, k = idx % K;
    out[idx] = f2b(in[(size_t)k * N + n]);
}

// ---------- K1: LN1 + roll(-3,-3) + window partition. x BCHW f32 -> xw [50176][384] bf16 ----------
__global__ __launch_bounds__(256) void ln1_gather_kernel(
    const float* __restrict__ x, const float* __restrict__ g,
    const float* __restrict__ bt, bf16* __restrict__ xw) {
    int wave = threadIdx.x >> 6, lane = threadIdx.x & 63;
    int T = blockIdx.x * 4 + wave;
    int wi = T / 49, n = T % 49;
    int b = wi >> 6, w64 = wi & 63;
    int bh = w64 >> 3, bw = w64 & 7;
    int hs = bh * 7 + n / 7 + 3; if (hs >= 56) hs -= 56;
    int wsd = bw * 7 + n % 7 + 3; if (wsd >= 56) wsd -= 56;
    const float* xp = x + (size_t)b * C_ * 3136 + hs * 56 + wsd;
    float v[6];
    #pragma unroll
    for (int k = 0; k < 6; k++) v[k] = xp[(size_t)(lane + k * 64) * 3136];
    float s = v[0] + v[1] + v[2] + v[3] + v[4] + v[5];
    #pragma unroll
    for (int m = 32; m; m >>= 1) s += __shfl_xor(s, m);
    float mu = s * (1.0f / 384.0f);
    float s2 = 0.f;
    #pragma unroll
    for (int k = 0; k < 6; k++) { float d = v[k] - mu; s2 += d * d; }
    #pragma unroll
    for (int m = 32; m; m >>= 1) s2 += __shfl_xor(s2, m);
    float rstd = rsqrtf(s2 * (1.0f / 384.0f) + 1e-5f);
    bf16* op = xw + (size_t)T * 384;
    #pragma unroll
    for (int k = 0; k < 6; k++) {
        int c = lane + k * 64;
        op[c] = f2b((v[k] - mu) * rstd * g[c] + bt[c]);
    }
}

// ---------- GEMM: C[M][N] = A[M][K] @ Wt[N][K]^T + bias ----------
// 256x128 tile, BK=64, 8 waves (4M x 2N, 64x64 per wave), 512 threads.
// Deep pipeline (T3+T4): 2 LDS K-tile buffers; stage tile t+2 into the buffer
// just freed by tile t; at the t->t+1 boundary wait vmcnt(6) (the 6 loads for
// t+2 stay in flight; t+1's older loads are thereby guaranteed complete).
// vmcnt never drains to 0 in the main loop. Raw s_barrier + sched_barrier fences.
// Swizzle: LDS granule g at row r holds global granule g^(r&7); reads XOR back
// (round-1-verified: 0 bank conflicts at BK=64).
enum { EPI_NONE = 0, EPI_GELU = 1, EPI_PROJ = 2, EPI_FC2 = 3 };

__device__ __forceinline__ void stage_tile(const bf16* const (&gA)[4], bf16* const (&lA)[4],
                                           const bf16* const (&gB)[2], bf16* const (&lB)[2],
                                           int k0) {
    #pragma unroll
    for (int p = 0; p < 4; p++) gld_lds16(gA[p] + k0, lA[p]);
    #pragma unroll
    for (int p = 0; p < 2; p++) gld_lds16(gB[p] + k0, lB[p]);
}

__device__ __forceinline__ void compute_tile(const bf16* Asb, const bf16* Bsb,
                                             int wr, int wc, int quad, int lm,
                                             f32x4 (&acc)[4][4]) {
    #pragma unroll
    for (int kk = 0; kk < 2; kk++) {
        bf16x8 af[4], bfr[4];
        #pragma unroll
        for (int i = 0; i < 4; i++) {
            int row = wr * 64 + i * 16 + lm;
            int g = (kk * 4 + quad) ^ (row & 7);
            af[i] = *(const bf16x8*)(Asb + row * 64 + g * 8);
        }
        #pragma unroll
        for (int j = 0; j < 4; j++) {
            int row = wc * 64 + j * 16 + lm;
            int g = (kk * 4 + quad) ^ (row & 7);
            bfr[j] = *(const bf16x8*)(Bsb + row * 64 + g * 8);
        }
        __builtin_amdgcn_s_setprio(1);
        #pragma unroll
        for (int j = 0; j < 4; j++)
            #pragma unroll
            for (int i = 0; i < 4; i++)
                acc[j][i] = __builtin_amdgcn_mfma_f32_16x16x32_bf16(bfr[j], af[i], acc[j][i], 0, 0, 0);
        __builtin_amdgcn_s_setprio(0);
    }
}

#define SYNC_FENCE() do { __builtin_amdgcn_sched_barrier(0); \
                          __builtin_amdgcn_s_barrier(); \
                          __builtin_amdgcn_sched_barrier(0); } while (0)

template <int EPI>
__global__ __launch_bounds__(512, 2) void gemm_kernel(
    const bf16* __restrict__ A, const bf16* __restrict__ Wt,
    const float* __restrict__ bias, bf16* __restrict__ Cout,
    int Kdim, int Ndim,
    const float* __restrict__ resx,   // EPI_PROJ: x in BCHW f32
    const bf16* __restrict__ resb) {  // EPI_FC2 : x2 token-major bf16
    __shared__ __align__(16) bf16 As[2][256 * 64];   // 64 KiB
    __shared__ __align__(16) bf16 Bs[2][128 * 64];   // 32 KiB
    int t = threadIdx.x;

    // n-inner linear order + XCD-chunked bijective remap (m204)
    int nwg = gridDim.x * gridDim.y;
    int bid = blockIdx.y * gridDim.x + blockIdx.x;
    int q8 = nwg >> 3, r8 = nwg & 7, xcd = bid & 7, off = bid >> 3;
    int swz = (xcd < r8 ? xcd * (q8 + 1) : r8 * (q8 + 1) + (xcd - r8) * q8) + off;
    int n0 = (swz % gridDim.x) * 128;
    int m0 = (swz / gridDim.x) * 256;

    int lane = t & 63, wave = t >> 6;          // wave 0..7
    int wr = wave >> 1, wc = wave & 1;         // wr 0..3 (M), wc 0..1 (N)
    int quad = lane >> 4, lm = lane & 15;
    f32x4 acc[4][4] = {};   // acc[j][i]: C^T frag. n = quad*4+reg, m = lm

    // staging maps: A = 2048 16B-chunks (256 rows x 8 granules) -> 4/thread;
    //               B = 1024 chunks (128 rows x 8) -> 2/thread.
    const bf16* gA[4]; bf16* lA0[4]; bf16* lA1[4];
    const bf16* gB[2]; bf16* lB0[2]; bf16* lB1[2];
    #pragma unroll
    for (int p = 0; p < 4; p++) {
        int idx = p * 512 + t;
        int row = idx >> 3, g = idx & 7;
        int gs = g ^ (row & 7);                // inverse swizzle on the SOURCE
        gA[p] = A + (size_t)(m0 + row) * Kdim + gs * 8;
        lA0[p] = &As[0][idx * 8]; lA1[p] = &As[1][idx * 8];   // linear LDS dest
    }
    #pragma unroll
    for (int p = 0; p < 2; p++) {
        int idx = p * 512 + t;
        int row = idx >> 3, g = idx & 7;
        int gs = g ^ (row & 7);
        gB[p] = Wt + (size_t)(n0 + row) * Kdim + gs * 8;
        lB0[p] = &Bs[0][idx * 8]; lB1[p] = &Bs[1][idx * 8];
    }

    int nt = Kdim >> 6;    // K-tiles of 64; 6 (K=384) or 24 (K=1536) -> always even
    // prologue: stage tiles 0,1; wait for tile0 only (tile1's 6 stay in flight)
    stage_tile(gA, lA0, gB, lB0, 0);
    stage_tile(gA, lA1, gB, lB1, 64);
    asm volatile("s_waitcnt vmcnt(6)" ::: "memory");
    SYNC_FENCE();

    for (int tk = 0; tk < nt; tk += 2) {
        // -------- even tile tk: buf0 --------
        compute_tile(As[0], Bs[0], wr, wc, quad, lm, acc);
        SYNC_FENCE();                            // all waves done reading buf0
        if (tk + 2 < nt) {
            stage_tile(gA, lA0, gB, lB0, (tk + 2) << 6);   // restage buf0
            asm volatile("s_waitcnt vmcnt(6)" ::: "memory"); // tile tk+1 landed
        } else {
            asm volatile("s_waitcnt vmcnt(0)" ::: "memory");
        }
        SYNC_FENCE();                            // rendezvous: buf1 ready everywhere
        // -------- odd tile tk+1: buf1 --------
        compute_tile(As[1], Bs[1], wr, wc, quad, lm, acc);
        if (tk + 2 < nt) {
            SYNC_FENCE();                        // all waves done reading buf1
            if (tk + 3 < nt) {
                stage_tile(gA, lA1, gB, lB1, (tk + 3) << 6);
                asm volatile("s_waitcnt vmcnt(6)" ::: "memory");
            } else {
                asm volatile("s_waitcnt vmcnt(0)" ::: "memory");
            }
            SYNC_FENCE();                        // rendezvous: buf0 ready everywhere
        }
    }

    // ---- epilogue: m = m0+wr*64+i*16+lm ; n = n0+wc*64+j*16+quad*4+r
    #pragma unroll
    for (int i = 0; i < 4; i++) {
        int m = m0 + wr * 64 + i * 16 + lm;
        size_t resbase = 0;
        if (EPI == EPI_PROJ) {
            int wi = m / 49, n_ = m % 49;
            int b = wi >> 6, w64 = wi & 63;
            int bh = w64 >> 3, bw = w64 & 7;
            int hs = bh * 7 + n_ / 7 + 3; if (hs >= 56) hs -= 56;
            int wsd = bw * 7 + n_ % 7 + 3; if (wsd >= 56) wsd -= 56;
            resbase = (size_t)b * C_ * 3136 + hs * 56 + wsd;
        }
        #pragma unroll
        for (int j = 0; j < 4; j++) {
            int nb = n0 + wc * 64 + j * 16 + quad * 4;
            f32x4 bj = *(const f32x4*)(bias + nb);
            f32x4 v;
            #pragma unroll
            for (int r = 0; r < 4; r++) v[r] = acc[j][i][r] + bj[r];
            if (EPI == EPI_GELU) {
                #pragma unroll
                for (int r = 0; r < 4; r++) v[r] = fast_gelu(v[r]);
            }
            if (EPI == EPI_PROJ) {
                #pragma unroll
                for (int r = 0; r < 4; r++) v[r] += resx[resbase + (size_t)(nb + r) * 3136];
            }
            if (EPI == EPI_FC2) {
                bf16x4 rb = *(const bf16x4*)(resb + (size_t)m * 384 + nb);
                #pragma unroll
                for (int r = 0; r < 4; r++) v[r] += b2f(rb[r]);
            }
            bf16x4 o;
            #pragma unroll
            for (int r = 0; r < 4; r++) o[r] = f2b(v[r]);
            *(bf16x4*)(Cout + (size_t)m * Ndim + nb) = o;
        }
    }
}

// ---------- K3: MFMA windowed attention. one wave-block per (window, head) ----------
__global__ __launch_bounds__(64) void attn_mfma_kernel(const bf16* __restrict__ qkv,
                                                       bf16* __restrict__ aout) {
    __shared__ __align__(16) bf16 pbuf[64 * 72];
    __shared__ int reg_[64];
    int l = threadIdx.x;
    int wi = blockIdx.x / 12, h = blockIdx.x % 12;
    int i16 = l & 15, quad = l >> 4;

    {
        int tok = l < 49 ? l : 48;
        int w64 = wi & 63;
        int bh = w64 >> 3, bw = w64 & 7;
        int hh = bh * 7 + tok / 7, ww = bw * 7 + tok % 7;
        int fh = hh < 49 ? 0 : (hh < 53 ? 1 : 2);
        int fw = ww < 49 ? 0 : (ww < 53 ? 1 : 2);
        reg_[l] = fh * 3 + fw;
    }
    __syncthreads();

    const bf16* qbase = qkv + (size_t)wi * 49 * 1152 + h * 32;

    // ---- S = Q @ K^T ----
    f32x4 s_[4][4] = {};   // [mi][nt], C-layout
    bf16x8 af[4], bfr[4];
    #pragma unroll
    for (int mi = 0; mi < 4; mi++) {
        int m = mi * 16 + i16; if (m > 48) m = 48;
        af[mi] = *(const bf16x8*)(qbase + (size_t)m * 1152 + quad * 8);
    }
    #pragma unroll
    for (int nt = 0; nt < 4; nt++) {
        int n = nt * 16 + i16; if (n > 48) n = 48;
        bfr[nt] = *(const bf16x8*)(qbase + 384 + (size_t)n * 1152 + quad * 8);
    }
    #pragma unroll
    for (int mi = 0; mi < 4; mi++)
        #pragma unroll
        for (int nt = 0; nt < 4; nt++)
            s_[mi][nt] = __builtin_amdgcn_mfma_f32_16x16x32_bf16(af[mi], bfr[nt], s_[mi][nt], 0, 0, 0);

    int creg[4];
    #pragma unroll
    for (int nt = 0; nt < 4; nt++) {
        int c = nt * 16 + i16; if (c > 48) c = 48;
        creg[nt] = reg_[c];
    }

    // ---- mask + softmax ----
    const float scale = 0.17677669529663687f;  // 1/sqrt(32)
    #pragma unroll
    for (int mi = 0; mi < 4; mi++) {
        #pragma unroll
        for (int r = 0; r < 4; r++) {
            int row = mi * 16 + quad * 4 + r;
            int rreg = reg_[row];
            float v[4]; float mx = -1e30f;
            #pragma unroll
            for (int nt = 0; nt < 4; nt++) {
                int c = nt * 16 + i16;
                float x = s_[mi][nt][r] * scale;
                if (c > 48) x = -1e30f;
                else if (rreg != creg[nt]) x -= 100.0f;
                v[nt] = x; mx = fmaxf(mx, x);
            }
            #pragma unroll
            for (int m = 8; m; m >>= 1) mx = fmaxf(mx, __shfl_xor(mx, m));
            float sum = 0.f;
            #pragma unroll
            for (int nt = 0; nt < 4; nt++) { v[nt] = __expf(v[nt] - mx); sum += v[nt]; }
            #pragma unroll
            for (int m = 8; m; m >>= 1) sum += __shfl_xor(sum, m);
            float inv = 1.0f / sum;
            #pragma unroll
            for (int nt = 0; nt < 4; nt++)
                pbuf[row * 72 + nt * 16 + i16] = f2b(v[nt] * inv);
        }
    }
    __syncthreads();

    // ---- O = P @ V ----
    f32x4 o_[4][2] = {};
    const bf16* vbase = qkv + (size_t)wi * 49 * 1152 + 768 + h * 32;
    #pragma unroll
    for (int ks = 0; ks < 2; ks++) {
        bf16x8 pa[4];
        #pragma unroll
        for (int mi = 0; mi < 4; mi++)
            pa[mi] = *(const bf16x8*)(pbuf + (mi * 16 + i16) * 72 + ks * 32 + quad * 8);
        bf16x8 vb[2];
        #pragma unroll
        for (int nt = 0; nt < 2; nt++)
            #pragma unroll
            for (int j = 0; j < 8; j++) {
                int tok = ks * 32 + quad * 8 + j; if (tok > 48) tok = 48;
                vb[nt][j] = vbase[(size_t)tok * 1152 + nt * 16 + i16];
            }
        #pragma unroll
        for (int mi = 0; mi < 4; mi++)
            #pragma unroll
            for (int nt = 0; nt < 2; nt++)
                o_[mi][nt] = __builtin_amdgcn_mfma_f32_16x16x32_bf16(pa[mi], vb[nt], o_[mi][nt], 0, 0, 0);
    }

    // ---- epilogue: write rows < 49 ----
    bf16* obase = aout + (size_t)wi * 49 * 384 + h * 32;
    #pragma unroll
    for (int mi = 0; mi < 4; mi++)
        #pragma unroll
        for (int r = 0; r < 4; r++) {
            int row = mi * 16 + quad * 4 + r;
            if (row < 49) {
                #pragma unroll
                for (int nt = 0; nt < 2; nt++)
                    obase[(size_t)row * 384 + nt * 16 + i16] = f2b(o_[mi][nt][r]);
            }
        }
}

// ---------- K5: LN2 on token-major bf16 ----------
__global__ __launch_bounds__(256) void ln2_kernel(const bf16* __restrict__ x2,
                                                  const float* __restrict__ g,
                                                  const float* __restrict__ bt,
                                                  bf16* __restrict__ x2n) {
    int wave = threadIdx.x >> 6, lane = threadIdx.x & 63;
    int T = blockIdx.x * 4 + wave;
    const bf16* xp = x2 + (size_t)T * 384;
    float v[6];
    #pragma unroll
    for (int k = 0; k < 6; k++) v[k] = b2f(xp[lane + k * 64]);
    float s = v[0] + v[1] + v[2] + v[3] + v[4] + v[5];
    #pragma unroll
    for (int m = 32; m; m >>= 1) s += __shfl_xor(s, m);
    float mu = s * (1.0f / 384.0f);
    float s2 = 0.f;
    #pragma unroll
    for (int k = 0; k < 6; k++) { float d = v[k] - mu; s2 += d * d; }
    #pragma unroll
    for (int m = 32; m; m >>= 1) s2 += __shfl_xor(s2, m);
    float rstd = rsqrtf(s2 * (1.0f / 384.0f) + 1e-5f);
    bf16* op = x2n + (size_t)T * 384;
    #pragma unroll
    for (int k = 0; k < 6; k++) {
        int c = lane + k * 64;
        op[c] = f2b((v[k] - mu) * rstd * g[c] + bt[c]);
    }
}

// ---------- K8: window reverse + unshift + transpose to BCHW f32 ----------
__global__ __launch_bounds__(256) void untile_kernel(const bf16* __restrict__ otok,
                                                     float* __restrict__ out) {
    __shared__ float tile[56 * 65];
    int t = threadIdx.x;
    int b = blockIdx.x / 336;       // 56*6
    int rem = blockIdx.x % 336;
    int h = rem / 6;
    int c0 = (rem % 6) * 64;
    int hs = h + 53; if (hs >= 56) hs -= 56;
    int bh = hs / 7, th = hs % 7;
    #pragma unroll
    for (int pass = 0; pass < 14; pass++) {
        int w = pass * 4 + (t >> 6);
        int c = t & 63;
        int wsd = w + 53; if (wsd >= 56) wsd -= 56;
        int T = (b * 64 + bh * 8 + wsd / 7) * 49 + th * 7 + wsd % 7;
        tile[w * 65 + c] = b2f(otok[(size_t)T * 384 + c0 + c]);
    }
    __syncthreads();
    #pragma unroll
    for (int pass = 0; pass < 14; pass++) {
        int idx = pass * 256 + t;
        int c = idx / 56, w = idx % 56;
        out[((size_t)(b * 384 + c0 + c)) * 3136 + h * 56 + w] = tile[w * 65 + c];
    }
}

// ---------- launcher ----------
extern "C" void kernel_launch(void* const* d_in, const int* in_sizes, int n_in,
                              void* d_out, int out_size, void* d_ws, size_t ws_size,
                              hipStream_t stream) {
    (void)in_sizes; (void)n_in; (void)out_size; (void)ws_size;
    const float* x      = (const float*)d_in[0];
    const float* n1g    = (const float*)d_in[1];
    const float* n1b    = (const float*)d_in[2];
    const float* qkv_w  = (const float*)d_in[3];
    const float* qkv_b  = (const float*)d_in[4];
    const float* proj_w = (const float*)d_in[5];
    const float* proj_b = (const float*)d_in[6];
    const float* n2g    = (const float*)d_in[7];
    const float* n2b    = (const float*)d_in[8];
    const float* fc1_w  = (const float*)d_in[9];
    const float* fc1_b  = (const float*)d_in[10];
    const float* fc2_w  = (const float*)d_in[11];
    const float* fc2_b  = (const float*)d_in[12];
    float* out = (float*)d_out;
    char* ws = (char*)d_ws;

    bf16* qkv_wT = (bf16*)(ws + 0);          // 884736 B
    bf16* proj_wT = (bf16*)(ws + 884736);    // 294912 B
    bf16* fc1_wT = (bf16*)(ws + 1179648);    // 1179648 B
    bf16* fc2_wT = (bf16*)(ws + 2359296);    // 1179648 B
    bf16* xw   = (bf16*)(ws + 4194304);      // 38535168 B
    bf16* qkvb = (bf16*)(ws + 42729472);     // 115605504 B
    bf16* attn = (bf16*)(ws + 158334976);    // 38535168 B
    bf16* x2   = (bf16*)(ws + 4194304);      // alias xw (dead)
    bf16* x2n  = (bf16*)(ws + 42729472);     // alias qkv (dead)
    bf16* h1   = (bf16*)(ws + 81264640);     // 154140672 B (overlaps dead attn)
    bf16* otok = (bf16*)(ws + 235405312);    // 38535168 B  (peak ws = 274 MB)

    wtrans_kernel<<<(384 * 1152 + 255) / 256, 256, 0, stream>>>(qkv_w, qkv_wT, 384, 1152);
    wtrans_kernel<<<(384 * 384 + 255) / 256, 256, 0, stream>>>(proj_w, proj_wT, 384, 384);
    wtrans_kernel<<<(384 * 1536 + 255) / 256, 256, 0, stream>>>(fc1_w, fc1_wT, 384, 1536);
    wtrans_kernel<<<(1536 * 384 + 255) / 256, 256, 0, stream>>>(fc2_w, fc2_wT, 1536, 384);

    ln1_gather_kernel<<<TOKENS / 4, 256, 0, stream>>>(x, n1g, n1b, xw);

    // grids: x = n-blocks (BN=128), y = m-panels (BM=256)
    gemm_kernel<EPI_NONE><<<dim3(9, 196), 512, 0, stream>>>(
        xw, qkv_wT, qkv_b, qkvb, 384, 1152, nullptr, nullptr);

    attn_mfma_kernel<<<12288, 64, 0, stream>>>(qkvb, attn);

    gemm_kernel<EPI_PROJ><<<dim3(3, 196), 512, 0, stream>>>(
        attn, proj_wT, proj_b, x2, 384, 384, x, nullptr);

    ln2_kernel<<<TOKENS / 4, 256, 0, stream>>>(x2, n2g, n2b, x2n);

    gemm_kernel<EPI_GELU><<<dim3(12, 196), 512, 0, stream>>>(
        x2n, fc1_wT, fc1_b, h1, 384, 1536, nullptr, nullptr);

    gemm_kernel<EPI_FC2><<<dim3(3, 196), 512, 0, stream>>>(
        h1, fc2_wT, fc2_b, otok, 1536, 384, nullptr, x2);

    untile_kernel<<<16 * 336, 256, 0, stream>>>(otok, out);
}

// Round 4
// 653.962 us; speedup vs baseline: 1.1298x; 1.0730x over previous
//
#include <hip/hip_runtime.h>
#include <hip/hip_bf16.h>
#include <math.h>
#include <stdint.h>

// ---------- constants ----------
#define C_ 384
#define TOKENS 50176          // B*H*W = 16*56*56 = 16*64*49

typedef __bf16 bf16;
typedef __bf16 bf16x8 __attribute__((ext_vector_type(8)));
typedef __bf16 bf16x4 __attribute__((ext_vector_type(4)));
typedef float  f32x4  __attribute__((ext_vector_type(4)));

__device__ __forceinline__ float b2f(bf16 x) { return (float)x; }
__device__ __forceinline__ bf16  f2b(float x) { return (bf16)x; }

// tanh-form GELU: v * sigmoid(1.5957691 v + 0.0713548 v^3)
__device__ __forceinline__ float fast_gelu(float v) {
    float u2 = v * fmaf(v * v, 0.07135481f, 1.5957691f);
    return v / (1.0f + __expf(-u2));
}

// async global->LDS, 16 bytes per lane. LDS dest must be wave-uniform base + lane*16.
__device__ __forceinline__ void gld_lds16(const bf16* g, bf16* l) {
    __builtin_amdgcn_global_load_lds(
        (const __attribute__((address_space(1))) void*)g,
        (__attribute__((address_space(3))) void*)l, 16, 0, 0);
}

// ---------- K0: weight convert+transpose: in f32 [K][N] -> out bf16 [N][K] ----------
__global__ void wtrans_kernel(const float* __restrict__ in, bf16* __restrict__ out,
                              int K, int N) {
    int idx = blockIdx.x * 256 + threadIdx.x;
    if (idx >= K * N) return;
    int n = idx / K, k = idx % K;
    out[idx] = f2b(in[(size_t)k * N + n]);
}

// ---------- K1: LN1 + roll(-3,-3) + window partition. x BCHW f32 -> xw [50176][384] bf16 ----------
__global__ __launch_bounds__(256) void ln1_gather_kernel(
    const float* __restrict__ x, const float* __restrict__ g,
    const float* __restrict__ bt, bf16* __restrict__ xw) {
    int wave = threadIdx.x >> 6, lane = threadIdx.x & 63;
    int T = blockIdx.x * 4 + wave;
    int wi = T / 49, n = T % 49;
    int b = wi >> 6, w64 = wi & 63;
    int bh = w64 >> 3, bw = w64 & 7;
    int hs = bh * 7 + n / 7 + 3; if (hs >= 56) hs -= 56;
    int wsd = bw * 7 + n % 7 + 3; if (wsd >= 56) wsd -= 56;
    const float* xp = x + (size_t)b * C_ * 3136 + hs * 56 + wsd;
    float v[6];
    #pragma unroll
    for (int k = 0; k < 6; k++) v[k] = xp[(size_t)(lane + k * 64) * 3136];
    float s = v[0] + v[1] + v[2] + v[3] + v[4] + v[5];
    #pragma unroll
    for (int m = 32; m; m >>= 1) s += __shfl_xor(s, m);
    float mu = s * (1.0f / 384.0f);
    float s2 = 0.f;
    #pragma unroll
    for (int k = 0; k < 6; k++) { float d = v[k] - mu; s2 += d * d; }
    #pragma unroll
    for (int m = 32; m; m >>= 1) s2 += __shfl_xor(s2, m);
    float rstd = rsqrtf(s2 * (1.0f / 384.0f) + 1e-5f);
    bf16* op = xw + (size_t)T * 384;
    #pragma unroll
    for (int k = 0; k < 6; k++) {
        int c = lane + k * 64;
        op[c] = f2b((v[k] - mu) * rstd * g[c] + bt[c]);
    }
}

// ---------- GEMM: C[M][N] = A[M][K] @ Wt[N][K]^T + bias ----------
// 128x128 tile, BK=64, 4 waves (2Mx2N, 64x64 each), 256 threads, 64 KiB LDS
// -> 2 blocks/CU. Double-buffered, counted vmcnt(8), never drains in main loop.
// Anti-serialization: per tile, ALL 16 ds_read_b128 are issued as one batch
// behind sched_barrier(0) fences, then all 32 MFMAs (setprio-wrapped). LDS
// addresses are 2 precomputed byte offsets (+compile-time imm): the swizzle
// granule g=(kk*4+quad)^(lm&7) is fragment-index-independent; kk flips bit 6.
enum { EPI_NONE = 0, EPI_GELU = 1, EPI_PROJ = 2, EPI_FC2 = 3 };

__device__ __forceinline__ void stage_tile(const bf16* const (&gA)[4], const bf16* const (&gB)[4],
                                           bf16* Asb, bf16* Bsb, int t, int k0) {
    #pragma unroll
    for (int p = 0; p < 4; p++) gld_lds16(gA[p] + k0, Asb + (p * 256 + t) * 8);
    #pragma unroll
    for (int p = 0; p < 4; p++) gld_lds16(gB[p] + k0, Bsb + (p * 256 + t) * 8);
}

__device__ __forceinline__ void compute_tile(const bf16* Asb, const bf16* Bsb,
                                             int aoff0, int aoff1, int boff0, int boff1,
                                             f32x4 (&acc)[4][4]) {
    bf16x8 af[2][4], bfr[2][4];
    __builtin_amdgcn_sched_barrier(0);
    #pragma unroll
    for (int i = 0; i < 4; i++) {
        af[0][i] = *(const bf16x8*)((const char*)Asb + aoff0 + i * 2048);
        af[1][i] = *(const bf16x8*)((const char*)Asb + aoff1 + i * 2048);
    }
    #pragma unroll
    for (int j = 0; j < 4; j++) {
        bfr[0][j] = *(const bf16x8*)((const char*)Bsb + boff0 + j * 2048);
        bfr[1][j] = *(const bf16x8*)((const char*)Bsb + boff1 + j * 2048);
    }
    __builtin_amdgcn_sched_barrier(0);
    __builtin_amdgcn_s_setprio(1);
    #pragma unroll
    for (int kk = 0; kk < 2; kk++)
        #pragma unroll
        for (int j = 0; j < 4; j++)
            #pragma unroll
            for (int i = 0; i < 4; i++)
                acc[j][i] = __builtin_amdgcn_mfma_f32_16x16x32_bf16(bfr[kk][j], af[kk][i], acc[j][i], 0, 0, 0);
    __builtin_amdgcn_s_setprio(0);
    __builtin_amdgcn_sched_barrier(0);
}

#define SYNC_FENCE() do { __builtin_amdgcn_sched_barrier(0); \
                          __builtin_amdgcn_s_barrier(); \
                          __builtin_amdgcn_sched_barrier(0); } while (0)

template <int EPI>
__global__ __launch_bounds__(256, 2) void gemm_kernel(
    const bf16* __restrict__ A, const bf16* __restrict__ Wt,
    const float* __restrict__ bias, bf16* __restrict__ Cout,
    int Kdim, int Ndim,
    const float* __restrict__ resx,   // EPI_PROJ: x in BCHW f32
    const bf16* __restrict__ resb) {  // EPI_FC2 : x2 token-major bf16
    __shared__ __align__(16) bf16 As[2][128 * 64];   // 32 KiB
    __shared__ __align__(16) bf16 Bs[2][128 * 64];   // 32 KiB
    int t = threadIdx.x;

    // n-inner linear order + XCD-chunked bijective remap (m204)
    int nwg = gridDim.x * gridDim.y;
    int bid = blockIdx.y * gridDim.x + blockIdx.x;
    int q8 = nwg >> 3, r8 = nwg & 7, xcd = bid & 7, off = bid >> 3;
    int swz = (xcd < r8 ? xcd * (q8 + 1) : r8 * (q8 + 1) + (xcd - r8) * q8) + off;
    int n0 = (swz % gridDim.x) * 128;
    int m0 = (swz / gridDim.x) * 128;

    int lane = t & 63, wave = t >> 6;          // 4 waves
    int wr = wave >> 1, wc = wave & 1;
    int quad = lane >> 4, lm = lane & 15;
    f32x4 acc[4][4] = {};   // acc[j][i]: C^T frag. n = quad*4+reg, m = lm

    // staging: 1024 16B-chunks per matrix (128 rows x 8 granules), 4/thread
    const bf16* gA[4]; const bf16* gB[4];
    #pragma unroll
    for (int p = 0; p < 4; p++) {
        int idx = p * 256 + t;
        int row = idx >> 3, g = idx & 7;
        int gs = g ^ (row & 7);                // inverse swizzle on the SOURCE
        gA[p] = A  + (size_t)(m0 + row) * Kdim + gs * 8;
        gB[p] = Wt + (size_t)(n0 + row) * Kdim + gs * 8;
    }

    // LDS byte offsets: row = (wr|wc)*64 + frag*16 + lm, granule = (kk*4+quad)^(lm&7)
    int g0 = quad ^ (lm & 7);
    int aoff0 = ((wr * 64 + lm) * 64 + g0 * 8) * 2;
    int boff0 = ((wc * 64 + lm) * 64 + g0 * 8) * 2;
    int aoff1 = aoff0 ^ 64;                    // kk=1: granule ^= 4 -> byte ^= 64
    int boff1 = boff0 ^ 64;

    int nt = Kdim >> 6;    // 6 (K=384) or 24 (K=1536): always even
    // prologue: stage tiles 0,1; wait tile0's 8 (tile1's 8 stay in flight)
    stage_tile(gA, gB, As[0], Bs[0], t, 0);
    stage_tile(gA, gB, As[1], Bs[1], t, 64);
    asm volatile("s_waitcnt vmcnt(8)" ::: "memory");
    SYNC_FENCE();

    for (int tk = 0; tk < nt; tk += 2) {
        // -------- even tile tk: buf0 --------
        compute_tile(As[0], Bs[0], aoff0, aoff1, boff0, boff1, acc);
        SYNC_FENCE();                            // all waves done reading buf0
        if (tk + 2 < nt) {
            stage_tile(gA, gB, As[0], Bs[0], t, (tk + 2) << 6);
            asm volatile("s_waitcnt vmcnt(8)" ::: "memory"); // tile tk+1 landed
        } else {
            asm volatile("s_waitcnt vmcnt(0)" ::: "memory");
        }
        SYNC_FENCE();                            // rendezvous: buf1 ready
        // -------- odd tile tk+1: buf1 --------
        compute_tile(As[1], Bs[1], aoff0, aoff1, boff0, boff1, acc);
        if (tk + 2 < nt) {
            SYNC_FENCE();                        // all waves done reading buf1
            if (tk + 3 < nt) {
                stage_tile(gA, gB, As[1], Bs[1], t, (tk + 3) << 6);
                asm volatile("s_waitcnt vmcnt(8)" ::: "memory");
            } else {
                asm volatile("s_waitcnt vmcnt(0)" ::: "memory");
            }
            SYNC_FENCE();                        // rendezvous: buf0 ready
        }
    }

    // ---- epilogue: m = m0+wr*64+i*16+lm ; n = n0+wc*64+j*16+quad*4+r
    #pragma unroll
    for (int i = 0; i < 4; i++) {
        int m = m0 + wr * 64 + i * 16 + lm;
        size_t resbase = 0;
        if (EPI == EPI_PROJ) {
            int wi = m / 49, n_ = m % 49;
            int b = wi >> 6, w64 = wi & 63;
            int bh = w64 >> 3, bw = w64 & 7;
            int hs = bh * 7 + n_ / 7 + 3; if (hs >= 56) hs -= 56;
            int wsd = bw * 7 + n_ % 7 + 3; if (wsd >= 56) wsd -= 56;
            resbase = (size_t)b * C_ * 3136 + hs * 56 + wsd;
        }
        #pragma unroll
        for (int j = 0; j < 4; j++) {
            int nb = n0 + wc * 64 + j * 16 + quad * 4;
            f32x4 bj = *(const f32x4*)(bias + nb);
            f32x4 v;
            #pragma unroll
            for (int r = 0; r < 4; r++) v[r] = acc[j][i][r] + bj[r];
            if (EPI == EPI_GELU) {
                #pragma unroll
                for (int r = 0; r < 4; r++) v[r] = fast_gelu(v[r]);
            }
            if (EPI == EPI_PROJ) {
                #pragma unroll
                for (int r = 0; r < 4; r++) v[r] += resx[resbase + (size_t)(nb + r) * 3136];
            }
            if (EPI == EPI_FC2) {
                bf16x4 rb = *(const bf16x4*)(resb + (size_t)m * 384 + nb);
                #pragma unroll
                for (int r = 0; r < 4; r++) v[r] += b2f(rb[r]);
            }
            bf16x4 o;
            #pragma unroll
            for (int r = 0; r < 4; r++) o[r] = f2b(v[r]);
            *(bf16x4*)(Cout + (size_t)m * Ndim + nb) = o;
        }
    }
}

// ---------- K3: MFMA windowed attention. one wave-block per (window, head) ----------
__global__ __launch_bounds__(64) void attn_mfma_kernel(const bf16* __restrict__ qkv,
                                                       bf16* __restrict__ aout) {
    __shared__ __align__(16) bf16 pbuf[64 * 72];
    __shared__ int reg_[64];
    int l = threadIdx.x;
    int wi = blockIdx.x / 12, h = blockIdx.x % 12;
    int i16 = l & 15, quad = l >> 4;

    {
        int tok = l < 49 ? l : 48;
        int w64 = wi & 63;
        int bh = w64 >> 3, bw = w64 & 7;
        int hh = bh * 7 + tok / 7, ww = bw * 7 + tok % 7;
        int fh = hh < 49 ? 0 : (hh < 53 ? 1 : 2);
        int fw = ww < 49 ? 0 : (ww < 53 ? 1 : 2);
        reg_[l] = fh * 3 + fw;
    }
    __syncthreads();

    const bf16* qbase = qkv + (size_t)wi * 49 * 1152 + h * 32;

    // ---- S = Q @ K^T ----
    f32x4 s_[4][4] = {};   // [mi][nt], C-layout
    bf16x8 af[4], bfr[4];
    #pragma unroll
    for (int mi = 0; mi < 4; mi++) {
        int m = mi * 16 + i16; if (m > 48) m = 48;
        af[mi] = *(const bf16x8*)(qbase + (size_t)m * 1152 + quad * 8);
    }
    #pragma unroll
    for (int nt = 0; nt < 4; nt++) {
        int n = nt * 16 + i16; if (n > 48) n = 48;
        bfr[nt] = *(const bf16x8*)(qbase + 384 + (size_t)n * 1152 + quad * 8);
    }
    #pragma unroll
    for (int mi = 0; mi < 4; mi++)
        #pragma unroll
        for (int nt = 0; nt < 4; nt++)
            s_[mi][nt] = __builtin_amdgcn_mfma_f32_16x16x32_bf16(af[mi], bfr[nt], s_[mi][nt], 0, 0, 0);

    int creg[4];
    #pragma unroll
    for (int nt = 0; nt < 4; nt++) {
        int c = nt * 16 + i16; if (c > 48) c = 48;
        creg[nt] = reg_[c];
    }

    // ---- mask + softmax ----
    const float scale = 0.17677669529663687f;  // 1/sqrt(32)
    #pragma unroll
    for (int mi = 0; mi < 4; mi++) {
        #pragma unroll
        for (int r = 0; r < 4; r++) {
            int row = mi * 16 + quad * 4 + r;
            int rreg = reg_[row];
            float v[4]; float mx = -1e30f;
            #pragma unroll
            for (int nt = 0; nt < 4; nt++) {
                int c = nt * 16 + i16;
                float x = s_[mi][nt][r] * scale;
                if (c > 48) x = -1e30f;
                else if (rreg != creg[nt]) x -= 100.0f;
                v[nt] = x; mx = fmaxf(mx, x);
            }
            #pragma unroll
            for (int m = 8; m; m >>= 1) mx = fmaxf(mx, __shfl_xor(mx, m));
            float sum = 0.f;
            #pragma unroll
            for (int nt = 0; nt < 4; nt++) { v[nt] = __expf(v[nt] - mx); sum += v[nt]; }
            #pragma unroll
            for (int m = 8; m; m >>= 1) sum += __shfl_xor(sum, m);
            float inv = 1.0f / sum;
            #pragma unroll
            for (int nt = 0; nt < 4; nt++)
                pbuf[row * 72 + nt * 16 + i16] = f2b(v[nt] * inv);
        }
    }
    __syncthreads();

    // ---- O = P @ V ----
    f32x4 o_[4][2] = {};
    const bf16* vbase = qkv + (size_t)wi * 49 * 1152 + 768 + h * 32;
    #pragma unroll
    for (int ks = 0; ks < 2; ks++) {
        bf16x8 pa[4];
        #pragma unroll
        for (int mi = 0; mi < 4; mi++)
            pa[mi] = *(const bf16x8*)(pbuf + (mi * 16 + i16) * 72 + ks * 32 + quad * 8);
        bf16x8 vb[2];
        #pragma unroll
        for (int nt = 0; nt < 2; nt++)
            #pragma unroll
            for (int j = 0; j < 8; j++) {
                int tok = ks * 32 + quad * 8 + j; if (tok > 48) tok = 48;
                vb[nt][j] = vbase[(size_t)tok * 1152 + nt * 16 + i16];
            }
        #pragma unroll
        for (int mi = 0; mi < 4; mi++)
            #pragma unroll
            for (int nt = 0; nt < 2; nt++)
                o_[mi][nt] = __builtin_amdgcn_mfma_f32_16x16x32_bf16(pa[mi], vb[nt], o_[mi][nt], 0, 0, 0);
    }

    // ---- epilogue: write rows < 49 ----
    bf16* obase = aout + (size_t)wi * 49 * 384 + h * 32;
    #pragma unroll
    for (int mi = 0; mi < 4; mi++)
        #pragma unroll
        for (int r = 0; r < 4; r++) {
            int row = mi * 16 + quad * 4 + r;
            if (row < 49) {
                #pragma unroll
                for (int nt = 0; nt < 2; nt++)
                    obase[(size_t)row * 384 + nt * 16 + i16] = f2b(o_[mi][nt][r]);
            }
        }
}

// ---------- K5: LN2 on token-major bf16 ----------
__global__ __launch_bounds__(256) void ln2_kernel(const bf16* __restrict__ x2,
                                                  const float* __restrict__ g,
                                                  const float* __restrict__ bt,
                                                  bf16* __restrict__ x2n) {
    int wave = threadIdx.x >> 6, lane = threadIdx.x & 63;
    int T = blockIdx.x * 4 + wave;
    const bf16* xp = x2 + (size_t)T * 384;
    float v[6];
    #pragma unroll
    for (int k = 0; k < 6; k++) v[k] = b2f(xp[lane + k * 64]);
    float s = v[0] + v[1] + v[2] + v[3] + v[4] + v[5];
    #pragma unroll
    for (int m = 32; m; m >>= 1) s += __shfl_xor(s, m);
    float mu = s * (1.0f / 384.0f);
    float s2 = 0.f;
    #pragma unroll
    for (int k = 0; k < 6; k++) { float d = v[k] - mu; s2 += d * d; }
    #pragma unroll
    for (int m = 32; m; m >>= 1) s2 += __shfl_xor(s2, m);
    float rstd = rsqrtf(s2 * (1.0f / 384.0f) + 1e-5f);
    bf16* op = x2n + (size_t)T * 384;
    #pragma unroll
    for (int k = 0; k < 6; k++) {
        int c = lane + k * 64;
        op[c] = f2b((v[k] - mu) * rstd * g[c] + bt[c]);
    }
}

// ---------- K8: window reverse + unshift + transpose to BCHW f32 ----------
__global__ __launch_bounds__(256) void untile_kernel(const bf16* __restrict__ otok,
                                                     float* __restrict__ out) {
    __shared__ float tile[56 * 65];
    int t = threadIdx.x;
    int b = blockIdx.x / 336;       // 56*6
    int rem = blockIdx.x % 336;
    int h = rem / 6;
    int c0 = (rem % 6) * 64;
    int hs = h + 53; if (hs >= 56) hs -= 56;
    int bh = hs / 7, th = hs % 7;
    #pragma unroll
    for (int pass = 0; pass < 14; pass++) {
        int w = pass * 4 + (t >> 6);
        int c = t & 63;
        int wsd = w + 53; if (wsd >= 56) wsd -= 56;
        int T = (b * 64 + bh * 8 + wsd / 7) * 49 + th * 7 + wsd % 7;
        tile[w * 65 + c] = b2f(otok[(size_t)T * 384 + c0 + c]);
    }
    __syncthreads();
    #pragma unroll
    for (int pass = 0; pass < 14; pass++) {
        int idx = pass * 256 + t;
        int c = idx / 56, w = idx % 56;
        out[((size_t)(b * 384 + c0 + c)) * 3136 + h * 56 + w] = tile[w * 65 + c];
    }
}

// ---------- launcher ----------
extern "C" void kernel_launch(void* const* d_in, const int* in_sizes, int n_in,
                              void* d_out, int out_size, void* d_ws, size_t ws_size,
                              hipStream_t stream) {
    (void)in_sizes; (void)n_in; (void)out_size; (void)ws_size;
    const float* x      = (const float*)d_in[0];
    const float* n1g    = (const float*)d_in[1];
    const float* n1b    = (const float*)d_in[2];
    const float* qkv_w  = (const float*)d_in[3];
    const float* qkv_b  = (const float*)d_in[4];
    const float* proj_w = (const float*)d_in[5];
    const float* proj_b = (const float*)d_in[6];
    const float* n2g    = (const float*)d_in[7];
    const float* n2b    = (const float*)d_in[8];
    const float* fc1_w  = (const float*)d_in[9];
    const float* fc1_b  = (const float*)d_in[10];
    const float* fc2_w  = (const float*)d_in[11];
    const float* fc2_b  = (const float*)d_in[12];
    float* out = (float*)d_out;
    char* ws = (char*)d_ws;

    bf16* qkv_wT = (bf16*)(ws + 0);          // 884736 B
    bf16* proj_wT = (bf16*)(ws + 884736);    // 294912 B
    bf16* fc1_wT = (bf16*)(ws + 1179648);    // 1179648 B
    bf16* fc2_wT = (bf16*)(ws + 2359296);    // 1179648 B
    bf16* xw   = (bf16*)(ws + 4194304);      // 38535168 B
    bf16* qkvb = (bf16*)(ws + 42729472);     // 115605504 B
    bf16* attn = (bf16*)(ws + 158334976);    // 38535168 B
    bf16* x2   = (bf16*)(ws + 4194304);      // alias xw (dead)
    bf16* x2n  = (bf16*)(ws + 42729472);     // alias qkv (dead)
    bf16* h1   = (bf16*)(ws + 81264640);     // 154140672 B (overlaps dead attn)
    bf16* otok = (bf16*)(ws + 235405312);    // 38535168 B  (peak ws = 274 MB)

    wtrans_kernel<<<(384 * 1152 + 255) / 256, 256, 0, stream>>>(qkv_w, qkv_wT, 384, 1152);
    wtrans_kernel<<<(384 * 384 + 255) / 256, 256, 0, stream>>>(proj_w, proj_wT, 384, 384);
    wtrans_kernel<<<(384 * 1536 + 255) / 256, 256, 0, stream>>>(fc1_w, fc1_wT, 384, 1536);
    wtrans_kernel<<<(1536 * 384 + 255) / 256, 256, 0, stream>>>(fc2_w, fc2_wT, 1536, 384);

    ln1_gather_kernel<<<TOKENS / 4, 256, 0, stream>>>(x, n1g, n1b, xw);

    // grids: x = n-blocks (BN=128), y = m-panels (BM=128)
    gemm_kernel<EPI_NONE><<<dim3(9, 392), 256, 0, stream>>>(
        xw, qkv_wT, qkv_b, qkvb, 384, 1152, nullptr, nullptr);

    attn_mfma_kernel<<<12288, 64, 0, stream>>>(qkvb, attn);

    gemm_kernel<EPI_PROJ><<<dim3(3, 392), 256, 0, stream>>>(
        attn, proj_wT, proj_b, x2, 384, 384, x, nullptr);

    ln2_kernel<<<TOKENS / 4, 256, 0, stream>>>(x2, n2g, n2b, x2n);

    gemm_kernel<EPI_GELU><<<dim3(12, 392), 256, 0, stream>>>(
        x2n, fc1_wT, fc1_b, h1, 384, 1536, nullptr, nullptr);

    gemm_kernel<EPI_FC2><<<dim3(3, 392), 256, 0, stream>>>(
        h1, fc2_wT, fc2_b, otok, 1536, 384, nullptr, x2);

    untile_kernel<<<16 * 336, 256, 0, stream>>>(otok, out);
}